// Round 13
// baseline (127.834 us; speedup 1.0000x reference)
//
#include <hip/hip_runtime.h>
#include <math.h>

// k' = c*8 + i (c-major): S-GEMM B-matrix is W's NATIVE [c][u][o][i] layout.
// cw-scaling fused into the B-fragment load (fixed (c,u) per 8-elem fragment),
// so the only dynamic cross-phase data is cwT (46 KB x3) and vT (330 KB x2).
// Two dispatches: k_prep, then persistent k_mega (S0,TB0,S1,TB1,S2; 4 flag barriers).
#define B_ 512
#define C_ 1152
#define U_ 10
#define O_ 16
#define I_ 8
#define K_ 9216
#define UO_ 160
#define NBLK 256
#define NTHR 1024

typedef short bf16x8 __attribute__((ext_vector_type(8)));
typedef float f32x4 __attribute__((ext_vector_type(4)));
typedef unsigned short u16x8v __attribute__((ext_vector_type(8)));
typedef unsigned long long u64t;

// ---- persistent device scratch (fully overwritten every call) ----
__device__ __attribute__((aligned(16))) unsigned short g_xb2[B_*K_];   // bf16 x [b][k']   (static)
__device__ __attribute__((aligned(16))) unsigned short g_xT2[K_*B_];   // bf16 x^T [k'][b] (static)
__device__ __attribute__((aligned(16))) unsigned short g_Wtb[C_*1280]; // bf16 W native layout (static)
__device__ __attribute__((aligned(16))) float g_cwT[3][U_*C_];         // routing weights [u][c], 3 versions
__device__ __attribute__((aligned(16))) unsigned g_vT32[2][UO_*B_/2];  // bf16 v^T packed u32, 2 versions
__device__ float g_b[C_*U_];           // logits (same block writes+reads its own c's)
__device__ unsigned g_gen;             // barrier generation (monotonic across replays)
__device__ unsigned g_arrive[NBLK];    // per-block arrival flags

__device__ __forceinline__ unsigned short f2bf(float f) {
    unsigned u = __builtin_bit_cast(unsigned, f);
    unsigned r = (u + 0x7FFFu + ((u >> 16) & 1u)) >> 16;
    return (unsigned short)r;
}

// scale a bf16x8 W-fragment by a scalar (fp32), repack to bf16 via v_cvt_pk
__device__ __forceinline__ bf16x8 scale8(u16x8v w, float s) {
    bf16x8 r;
    #pragma unroll
    for (int p = 0; p < 4; p++) {
        float lo = __builtin_bit_cast(float, ((unsigned)w[2*p])   << 16) * s;
        float hi = __builtin_bit_cast(float, ((unsigned)w[2*p+1]) << 16) * s;
        unsigned pk;
        asm("v_cvt_pk_bf16_f32 %0, %1, %2" : "=v"(pk) : "v"(lo), "v"(hi));
        r[2*p]   = (short)(pk & 0xFFFFu);
        r[2*p+1] = (short)(pk >> 16);
    }
    return r;
}

// ---- dispatch 1: prep. x -> bf16 [b][k'] + [k'][b]; Wtb = bf16(W); cwT[0]=0.1 ----
__global__ __launch_bounds__(256) void k_prep(const float* __restrict__ x,
                                              const float* __restrict__ W) {
    __shared__ unsigned short lds[32*256];
    int task = blockIdx.x, tid = threadIdx.x;
    if (task < 576) {
        int b0 = (task & 15) * 32;
        int c0 = (task >> 4) * 32;
        int li = tid >> 5, lc = tid & 31;
        for (int rep = 0; rep < 32; rep++) {
            float v = x[(b0+rep)*K_ + li*1152 + c0 + lc];
            lds[rep*256 + ((lc*8+li) ^ ((rep&31)<<3))] = f2bf(v);
        }
        __syncthreads();
        {   // xb2: 32 contiguous elems per thread
            int b = tid >> 3, part = tid & 7;
            int swz = (b&31) << 3;
            const u16x8v* lv = (const u16x8v*)lds;
            u16x8v* ov = (u16x8v*)(g_xb2 + (b0+b)*K_ + c0*8 + part*32);
            #pragma unroll
            for (int g = 0; g < 4; g++)
                ov[g] = lv[(b*256 + ((part*32 + g*8) ^ swz)) >> 3];
        }
        for (int p = 0; p < 8; p++) {   // xT2: 8 threads per k'-row
            int r = p*32 + (tid>>3);
            int bp = (tid&7)*4;
            ushort4 o;
            unsigned short* po = (unsigned short*)&o;
            #pragma unroll
            for (int q = 0; q < 4; q++) {
                int b = bp + q;
                po[q] = lds[b*256 + (r ^ ((b&31)<<3))];
            }
            *(ushort4*)(g_xT2 + (c0*8 + r)*B_ + b0 + bp) = o;
        }
    } else if (task < 756) {
        int base = (task - 576) * 8192;
        for (int j = 0; j < 8; j++) {
            float4 v = *(const float4*)(W + base + j*1024 + tid*4);
            ushort4 o;
            o.x = f2bf(v.x); o.y = f2bf(v.y);
            o.z = f2bf(v.z); o.w = f2bf(v.w);
            *(ushort4*)(g_Wtb + base + j*1024 + tid*4) = o;
        }
    } else {
        for (int i = tid; i < U_*C_; i += 256) g_cwT[0][i] = 0.1f;
    }
}

struct TBsh { float agg[2][U_]; float cws[2][U_]; };
union ShMem {
    float red[16][16][32];        // 32 KB (S-phase cross-wave reduce)
    TBsh tb[4];                   // 4 concurrent TB task-groups
};

// ---- grid barrier: flag arrive + block-0 sweep + gen broadcast; no fences ----
__device__ __forceinline__ void gbar(unsigned target) {
    __syncthreads();                    // drains vmcnt: payload stores at coherence point
    if (threadIdx.x == 0)
        __hip_atomic_store(&g_arrive[blockIdx.x], target,
                           __ATOMIC_RELAXED, __HIP_MEMORY_SCOPE_SYSTEM);
    if (blockIdx.x == 0) {
        long spins = 0;
        for (;;) {
            int ok = 1;
            if (threadIdx.x < NBLK) {
                unsigned a = __hip_atomic_load(&g_arrive[threadIdx.x],
                                               __ATOMIC_RELAXED, __HIP_MEMORY_SCOPE_SYSTEM);
                ok = (int)(a - target) >= 0;
            }
            if (__syncthreads_count(ok) == NTHR) break;
            __builtin_amdgcn_s_sleep(4);
            if (++spins > (1L << 17)) break;        // failsafe: fail fast, never hang
        }
        if (threadIdx.x == 0)
            __hip_atomic_store(&g_gen, target, __ATOMIC_RELAXED, __HIP_MEMORY_SCOPE_SYSTEM);
    }
    if (threadIdx.x == 0) {
        long spins = 0;
        while ((int)(__hip_atomic_load(&g_gen, __ATOMIC_RELAXED, __HIP_MEMORY_SCOPE_SYSTEM) - target) < 0) {
            __builtin_amdgcn_s_sleep(8);
            if (++spins > (1L << 18)) break;        // failsafe
        }
    }
    __syncthreads();
}

// ---- phase: S = x @ (cw.Wtb)^T fused with squash -> vT (+ final out). 160 tasks. ----
// 16 waves split K (576 k' each, 18 MFMA iters); cw scaling fused per fragment.
// Idle blocks (bid>=160) warm their XCD's L2 with their TB-phase xT2/W slices.
__device__ void ph_s(const float* __restrict__ cwv, unsigned* vtw,
                     const float* __restrict__ W, float* __restrict__ out,
                     int bid, int tid, ShMem& sh) {
    if (bid < 160) {
        int lane = tid & 63, w = tid >> 6;          // w = 0..15
        int mt = bid & 31, nt = bid >> 5;
        int m0 = mt*16, n0 = nt*32;
        int ra = lane & 15;
        const unsigned short* pa  = g_xb2 + (m0+ra)*K_ + w*576 + (lane>>4)*8;
        const unsigned short* pw0 = g_Wtb + (w*72 + (lane>>4))*1280 + (n0+ra)*8;
        const unsigned short* pw1 = pw0 + 128;
        const float* pc = cwv + (2*nt)*C_ + w*72 + (lane>>4);
        f32x4 acc0 = {0.f,0.f,0.f,0.f};
        f32x4 acc1 = {0.f,0.f,0.f,0.f};
        #pragma unroll 6
        for (int s = 0; s < 18; s++) {              // K/wave = 576
            bf16x8 a  = *(const bf16x8*)pa;
            u16x8v w0 = *(const u16x8v*)pw0;
            u16x8v w1 = *(const u16x8v*)pw1;
            float s0 = pc[0];
            float s1 = pc[C_];
            bf16x8 b0 = scale8(w0, s0);
            bf16x8 b1 = scale8(w1, s1);
            acc0 = __builtin_amdgcn_mfma_f32_16x16x32_bf16(a, b0, acc0, 0, 0, 0);
            acc1 = __builtin_amdgcn_mfma_f32_16x16x32_bf16(a, b1, acc1, 0, 0, 0);
            pa += 32; pw0 += 5120; pw1 += 5120; pc += 4;   // +4 channels
        }
        int row = (lane>>4)*4, col = lane & 15;
        #pragma unroll
        for (int r = 0; r < 4; r++) {
            sh.red[w][row+r][col]    = acc0[r];
            sh.red[w][row+r][col+16] = acc1[r];
        }
        __syncthreads();
        if (tid < 256) {
            int bp = tid >> 5;              // 0..7
            int u  = (tid >> 4) & 1;
            int o  = tid & 15;
            int col2 = u*16 + o;
            float t0 = 0.f, t1 = 0.f;
            #pragma unroll
            for (int ww = 0; ww < 16; ww++) {
                t0 += sh.red[ww][2*bp][col2];
                t1 += sh.red[ww][2*bp+1][col2];
            }
            float n0s = t0*t0, n1s = t1*t1;
            #pragma unroll
            for (int m = 1; m < 16; m <<= 1) {
                n0s += __shfl_xor(n0s, m);
                n1s += __shfl_xor(n1s, m);
            }
            float f0 = n0s / ((1.f + n0s) * sqrtf(n0s));
            float f1 = n1s / ((1.f + n1s) * sqrtf(n1s));
            float v0 = t0*f0, v1 = t1*f1;
            int ug = nt*2 + u;
            int bg = m0 + 2*bp;
            if (vtw) {
                unsigned pack = (unsigned)f2bf(v0) | ((unsigned)f2bf(v1) << 16);
                __hip_atomic_store(&vtw[((ug*16+o)*B_ + bg) >> 1], pack,
                                   __ATOMIC_RELAXED, __HIP_MEMORY_SCOPE_SYSTEM);
            } else {
                out[(bg*10 + ug)*16 + o]       = v0;
                out[((bg+1)*10 + ug)*16 + o]   = v1;
            }
        }
        __syncthreads();                        // sh.red safe before next phase
    } else {
        // idle blocks: warm this XCD's L2 with our TB tasks' xT2 (16KB) + W (10KB) slices
        float sink = 0.f;
        #pragma unroll
        for (int g2 = 0; g2 < 3; g2++) {
            int t = bid + 256*g2;
            if (t < 576) {
                if (tid < 256) {
                    const float* p = (const float*)((const char*)g_xT2 + t*16384) + tid*16;
                    sink += *p;
                }
                if (tid >= 256 && tid < 416) {
                    const float* p = W + t*2560 + (tid-256)*16;
                    sink += *p;
                }
            }
        }
        asm volatile("" :: "v"(sink));
        __syncthreads();
        __syncthreads();
    }
}

// ---- phase: TB. 4 groups x 4 waves; group g runs task bid+256g. 576 tasks. ----
// T' in regs + agree(W fp32) + b-update + softmax -> cwT (80B/task, write-through)
__device__ void ph_tb(const float* __restrict__ W, const unsigned* vtr,
                      float* cww, int first, int bid, int tid, ShMem& sh) {
    int lane = tid & 63, lw = (tid >> 6) & 3, g = tid >> 8;
    int ltid = tid & 255;
    int t = bid + 256*g;
    int valid = (t < 576);
    const unsigned short* vT = (const unsigned short*)vtr;
    int c0 = t * 2;
    int ra = lane & 15, kq = (lane>>4)*8;
    int ct = lane >> 5;
    int i0 = ((lane>>4) & 1) * 4;
    int o  = lane & 15;
    if (valid) {
        const unsigned short* pa0 = g_xT2 + (c0*8 + ra)*B_ + kq;
        for (int nt = lw; nt < 5; nt += 4) {    // wave lw=0 also covers tile 4
            int n0 = nt*32;
            const unsigned short* pa  = pa0;
            const unsigned short* pb0 = vT + (n0+ra)*B_ + kq;
            const unsigned short* pb1 = pb0 + 16*B_;
            f32x4 acc0 = {0.f,0.f,0.f,0.f};
            f32x4 acc1 = {0.f,0.f,0.f,0.f};
            #pragma unroll 4
            for (int s = 0; s < 16; s++) {      // K = 512
                bf16x8 a  = *(const bf16x8*)pa;
                bf16x8 b0 = *(const bf16x8*)pb0;
                bf16x8 b1 = *(const bf16x8*)pb1;
                acc0 = __builtin_amdgcn_mfma_f32_16x16x32_bf16(a, b0, acc0, 0, 0, 0);
                acc1 = __builtin_amdgcn_mfma_f32_16x16x32_bf16(a, b1, acc1, 0, 0, 0);
                pa += 32; pb0 += 32; pb1 += 32;
            }
            const float* wr = W + (c0+ct)*1280;
            float4 wa = *(const float4*)(wr + (2*nt  )*128 + o*8 + i0);
            float4 wb = *(const float4*)(wr + (2*nt+1)*128 + o*8 + i0);
            float p0 = wa.x*acc0[0] + wa.y*acc0[1] + wa.z*acc0[2] + wa.w*acc0[3];
            float p1 = wb.x*acc1[0] + wb.y*acc1[1] + wb.z*acc1[2] + wb.w*acc1[3];
            #pragma unroll
            for (int m = 1; m < 32; m <<= 1) {
                p0 += __shfl_xor(p0, m);
                p1 += __shfl_xor(p1, m);
            }
            if ((lane & 31) == 0) {
                sh.tb[g].agg[ct][2*nt]   = p0 * (1.f/512.f);
                sh.tb[g].agg[ct][2*nt+1] = p1 * (1.f/512.f);
            }
        }
    }
    __syncthreads();
    if (valid && ltid < 2) {                    // per-channel b-update + softmax
        int c = c0 + ltid;
        float bv[U_];
        float mx = -3e38f;
        #pragma unroll
        for (int u = 0; u < U_; u++) {
            float v = sh.tb[g].agg[ltid][u];
            if (!first) v += g_b[c*U_ + u];
            g_b[c*U_ + u] = v;
            bv[u] = v;
            mx = fmaxf(mx, v);
        }
        float sm = 0.f;
        #pragma unroll
        for (int u = 0; u < U_; u++) { bv[u] = expf(bv[u] - mx); sm += bv[u]; }
        float inv = 1.f/sm;
        #pragma unroll
        for (int u = 0; u < U_; u++) sh.tb[g].cws[ltid][u] = bv[u]*inv;
    }
    __syncthreads();
    if (valid && ltid < 20) {                   // next-iter cwT, write-through (80 B/task)
        int u = ltid >> 1, ch = ltid & 1;
        __hip_atomic_store(&cww[u*C_ + c0 + ch], sh.tb[g].cws[ch][u],
                           __ATOMIC_RELAXED, __HIP_MEMORY_SCOPE_SYSTEM);
    }
    __syncthreads();                            // sh.tb safe before next phase
}

// ---- dispatch 2: persistent kernel, 5 phases, 4 flag barriers ----
__global__ __launch_bounds__(NTHR) void k_mega(const float* __restrict__ W,
                                               float* __restrict__ out) {
    __shared__ ShMem sh;
    __shared__ unsigned sG0;
    int bid = blockIdx.x, tid = threadIdx.x;
    if (tid == 0)
        sG0 = __hip_atomic_load(&g_gen, __ATOMIC_RELAXED, __HIP_MEMORY_SCOPE_SYSTEM);
    __syncthreads();
    unsigned G0 = sG0;
    ph_s(g_cwT[0], &g_vT32[0][0], W, out, bid, tid, sh);    // t=0 (cw = 0.1)
    gbar(G0 + 1);
    ph_tb(W, &g_vT32[0][0], g_cwT[1], 1, bid, tid, sh);
    gbar(G0 + 2);
    ph_s(g_cwT[1], &g_vT32[1][0], W, out, bid, tid, sh);    // t=1
    gbar(G0 + 3);
    ph_tb(W, &g_vT32[1][0], g_cwT[2], 0, bid, tid, sh);
    gbar(G0 + 4);
    ph_s(g_cwT[2], nullptr, W, out, bid, tid, sh);          // t=2 -> final output
}

extern "C" void kernel_launch(void* const* d_in, const int* in_sizes, int n_in,
                              void* d_out, int out_size, void* d_ws, size_t ws_size,
                              hipStream_t stream) {
    const float* x = (const float*)d_in[0];
    const float* W = (const float*)d_in[1];
    float* out = (float*)d_out;
    k_prep<<<dim3(757), dim3(256), 0, stream>>>(x, W);
    k_mega<<<dim3(NBLK), dim3(NTHR), 0, stream>>>(W, out);
}